// Round 6
// baseline (302.494 us; speedup 1.0000x reference)
//
#include <hip/hip_runtime.h>
#include <hip/hip_bf16.h>
#include <math.h>

// Problem constants: B=4, L=2048, D=1024, H=16, hd=64
// M = B*L = 8192, QKV N = 3072, proj N = 1024, K = 1024

typedef unsigned short u16;
typedef __attribute__((ext_vector_type(8))) short bf8;   // 8 bf16 = 4 VGPR (MFMA A/B frag, K=32)
typedef __attribute__((ext_vector_type(4))) short bf4;   // 4 bf16 = 2 VGPR (MFMA A/B frag, K=16)
typedef __attribute__((ext_vector_type(4))) float f4;    // MFMA C/D frag

__device__ __forceinline__ u16 f2bf(float f) {
  unsigned int u = __float_as_uint(f);
  unsigned int r = (u + 0x7fffu + ((u >> 16) & 1u)) >> 16;
  return (u16)r;
}

__device__ __forceinline__ unsigned cvtpk_bf16(float lo, float hi) {
  unsigned r;
  asm("v_cvt_pk_bf16_f32 %0, %1, %2" : "=v"(r) : "v"(lo), "v"(hi));
  return r;
}

__device__ __forceinline__ f4 mfma16(bf8 a, bf8 b, f4 c) {
  return __builtin_amdgcn_mfma_f32_16x16x32_bf16(a, b, c, 0, 0, 0);
}

__device__ __forceinline__ f4 mfma16x16(bf4 a, bf4 b, f4 c) {
#if __has_builtin(__builtin_amdgcn_mfma_f32_16x16x16bf16_1k)
  return __builtin_amdgcn_mfma_f32_16x16x16bf16_1k(a, b, c, 0, 0, 0);
#elif __has_builtin(__builtin_amdgcn_mfma_f32_16x16x16_bf16)
  return __builtin_amdgcn_mfma_f32_16x16x16_bf16(a, b, c, 0, 0, 0);
#else
  f4 d;
  asm volatile("v_mfma_f32_16x16x16_bf16 %0, %1, %2, %3"
               : "=v"(d) : "v"(a), "v"(b), "v"(c));
  return d;
#endif
}

__device__ __forceinline__ float fexp2(float x) {
#if __has_builtin(__builtin_amdgcn_exp2f)
  return __builtin_amdgcn_exp2f(x);
#else
  return exp2f(x);
#endif
}

__device__ __forceinline__ void async_copy16(const void* gsrc, void* ldst) {
  __builtin_amdgcn_global_load_lds(
      (__attribute__((address_space(1))) void*)gsrc,
      (__attribute__((address_space(3))) void*)ldst,
      16, 0, 0);
}

// ---------------- prep kernels ----------------

__global__ __launch_bounds__(256) void convert_bf16_k(const float* __restrict__ in,
                                                      u16* __restrict__ out, int n4) {
  int i = blockIdx.x * blockDim.x + threadIdx.x;
  if (i < n4) {
    float4 v = ((const float4*)in)[i];
    ushort4 o;
    o.x = f2bf(v.x); o.y = f2bf(v.y); o.z = f2bf(v.z); o.w = f2bf(v.w);
    ((ushort4*)out)[i] = o;
  }
}

// in [K][N] f32 row-major -> out [N][K] bf16 row-major (B^T layout). 64x64 tiles.
__global__ __launch_bounds__(256) void transpose_bf16_k(const float* __restrict__ in,
                                                        u16* __restrict__ out, int K, int N) {
  __shared__ float t[64][65];
  int k0 = blockIdx.x * 64;
  int n0 = blockIdx.y * 64;
  int tx = threadIdx.x & 63, ty = threadIdx.x >> 6;  // 4 rows per pass
  for (int i = 0; i < 16; i++) {
    int r = ty + i * 4;
    t[r][tx] = in[(size_t)(k0 + r) * N + n0 + tx];
  }
  __syncthreads();
  for (int i = 0; i < 16; i++) {
    int r = ty + i * 4;
    out[(size_t)(n0 + r) * K + k0 + tx] = f2bf(t[tx][r]);
  }
}

// cos/sin tables [2048][32] f32
__global__ __launch_bounds__(256) void rope_tables_k(float* __restrict__ cosT,
                                                     float* __restrict__ sinT) {
  int i = blockIdx.x * blockDim.x + threadIdx.x;  // 65536
  int l = i >> 5, j = i & 31;
  float inv = powf(10000.0f, -(float)j / 32.0f);
  float f = (float)l * inv;
  cosT[i] = cosf(f);
  sinT[i] = sinf(f);
}

// ---------------- GEMM (A[M][K]bf16 x Bt[N][K]bf16) ---- R2-proven structure ----
// 128x128 tile, BK=64, 4 waves (2x2), each wave 64x64 (4x4 frags of 16x16x32).
// LDS tiles are [128 rows][128 bytes] with XOR swizzle byte ^= ((row&7)<<4),
// applied on the global SOURCE address (global_load_lds writes linearly) and on reads.
// EPI==0: out f32 += bias. EPI==1: fused bias+RoPE epilogue -> Qb/Kb [bh][l][64], Vt [bh][64][l].

template <int EPI>
__global__ __launch_bounds__(256, 2) void gemm_bt(
    const u16* __restrict__ A, const u16* __restrict__ Bt, const float* __restrict__ bias,
    float* __restrict__ outF,
    u16* __restrict__ Qb, u16* __restrict__ Kb, u16* __restrict__ Vt,
    const float* __restrict__ cosT, const float* __restrict__ sinT,
    int M, int N, int K) {
  __shared__ __attribute__((aligned(16))) u16 lA[128 * 64];
  __shared__ __attribute__((aligned(16))) u16 lB[128 * 64];
  const int tid = threadIdx.x;
  const int lane = tid & 63, wid = tid >> 6;
  const int nTilesN = N >> 7;
  const int bm = blockIdx.x / nTilesN, bn = blockIdx.x % nTilesN;
  const int m0 = bm << 7, n0 = bn << 7;
  const int wm = (wid >> 1) << 6, wn = (wid & 1) << 6;
  const int g = lane >> 4, c0 = lane & 15;

  f4 acc[4][4];
  for (int i = 0; i < 4; i++)
    for (int j = 0; j < 4; j++) acc[i][j] = (f4)0.0f;

  for (int k0 = 0; k0 < K; k0 += 64) {
    __syncthreads();
    for (int i = 0; i < 4; i++) {
      int chunk = i * 4 + wid;
      int p = chunk * 1024 + lane * 16;
      int row = p >> 7, pb = p & 127;
      int lb = pb ^ ((row & 7) << 4);
      async_copy16((const char*)(A + (size_t)(m0 + row) * K + k0) + lb,
                   (char*)lA + chunk * 1024);
    }
    for (int i = 0; i < 4; i++) {
      int chunk = i * 4 + wid;
      int p = chunk * 1024 + lane * 16;
      int row = p >> 7, pb = p & 127;
      int lb = pb ^ ((row & 7) << 4);
      async_copy16((const char*)(Bt + (size_t)(n0 + row) * K + k0) + lb,
                   (char*)lB + chunk * 1024);
    }
    __syncthreads();
    bf8 a[4][2], b[4][2];
    for (int ks = 0; ks < 2; ks++) {
      int cb = ks * 64 + g * 16;
      for (int mf = 0; mf < 4; mf++) {
        int row = wm + mf * 16 + c0;
        a[mf][ks] = *(const bf8*)((const char*)lA + (row << 7) + (cb ^ ((row & 7) << 4)));
      }
      for (int nf = 0; nf < 4; nf++) {
        int row = wn + nf * 16 + c0;
        b[nf][ks] = *(const bf8*)((const char*)lB + (row << 7) + (cb ^ ((row & 7) << 4)));
      }
    }
    for (int ks = 0; ks < 2; ks++)
      for (int mf = 0; mf < 4; mf++)
        for (int nf = 0; nf < 4; nf++)
          acc[mf][nf] = mfma16(a[mf][ks], b[nf][ks], acc[mf][nf]);
  }

  // C frag mapping (verified m89/m91): col = c0 + 16*nf (+wn+n0), row = 4*g + reg (+16*mf+wm+m0)
  if (EPI == 0) {
    for (int nf = 0; nf < 4; nf++) {
      int col = n0 + wn + nf * 16 + c0;
      float bv = bias[col];
      for (int mf = 0; mf < 4; mf++) {
        int rowb = m0 + wm + mf * 16 + g * 4;
        for (int r = 0; r < 4; r++)
          outF[(size_t)(rowb + r) * N + col] = acc[mf][nf][r] + bv;
      }
    }
  } else {
    for (int nf = 0; nf < 4; nf++) {
      int col = n0 + wn + nf * 16 + c0;
      int sec = col >> 10;          // 0=q 1=k 2=v
      int hc = col & 1023;
      int h = hc >> 6, d = hc & 63;
      float bv = bias[col];
      int pcol = n0 + wn + (nf ^ 2) * 16 + c0;  // RoPE partner col (d +/- 32), same lane
      float pbv = bias[pcol];
      for (int mf = 0; mf < 4; mf++) {
        int rowb = m0 + wm + mf * 16 + g * 4;
        for (int r = 0; r < 4; r++) {
          int row = rowb + r;
          int bb = row >> 11, l = row & 2047;
          int bh = bb * 16 + h;
          float v = acc[mf][nf][r] + bv;
          if (sec == 2) {
            Vt[((size_t)bh * 64 + d) * 2048 + l] = f2bf(v);  // V stored transposed [bh][d][l]
          } else {
            int dm = d & 31;
            float cz = cosT[l * 32 + dm], sz = sinT[l * 32 + dm];
            float pv = acc[mf][nf ^ 2][r] + pbv;
            float o = (d < 32) ? (v * cz - pv * sz) : (v * cz + pv * sz);
            u16* dst = (sec == 0) ? Qb : Kb;
            dst[((size_t)bh * 2048 + l) * 64 + d] = f2bf(o);
          }
        }
      }
    }
  }
}

// ---------------- flash attention v3 (mask-fix) ----------------
// 256 blocks = 64 bh x 4 q-tile-pairs (q-tile = 256 rows). Block handles q-tiles
// (pi) and (7-pi): exactly 36 KV-tile-steps each -> perfectly balanced.
// 512 threads = 8 waves x 32 q-rows. KV tile 64.
// 3-buffer lag-2 staging with counted vmcnt(2) + raw s_barrier (one per step);
// sched_barrier(0) after each s_barrier pins post-barrier ds_reads (rule #18).
// MASK RULE: wave q-range is [qw, qw+31]; mask needed iff kv0+63 > qw (q_min!),
// NOT qw+31 -- R5's bug let odd-wid waves attend up to 31 future positions.
// S^T = mfma(K, Q): lane owns one q-row; softmax lane-local + 2 shfl_xor; P is
// directly the 16x16x16 PV B-fragment (k = 4g + r): no LDS round-trip.
// cvt_pk bf16 pack (T12), defer-max THR=8 (T13, exact math), setprio (T5).
__global__ __launch_bounds__(512, 4) void attn_fwd(
    const u16* __restrict__ Qb, const u16* __restrict__ Kb, const u16* __restrict__ Vt,
    u16* __restrict__ attnOut) {
  __shared__ __attribute__((aligned(16))) u16 kT[3][64 * 64];
  __shared__ __attribute__((aligned(16))) u16 vT[3][64 * 64];
  const int tid = threadIdx.x, lane = tid & 63, wid = tid >> 6;
  // XCD swizzle: 32 consecutive lblk (8 bh) per XCD -> K/V 4MB = one L2
  const int pblk = blockIdx.x;                 // nwg = 256
  const int lblk = ((pblk & 7) << 5) | (pblk >> 3);
  const int bh = lblk >> 2, pi = lblk & 3;
  const int bb = bh >> 4, h = bh & 15;
  const u16* Qp = Qb + (size_t)bh * 2048 * 64;
  const u16* Kp = Kb + (size_t)bh * 2048 * 64;
  const u16* Vp = Vt + (size_t)bh * 64 * 2048;   // [64 d][2048 l]
  const int g = lane >> 4, c0 = lane & 15;
  const float sc = 0.125f * 1.4426950408889634f;  // scale * log2(e)

  // one K-load + one V-load per thread per tile (512 threads x 16B = 8KB each)
  const int soff = tid * 16;
  const int srow = soff >> 7, spb = soff & 127;
  const int slb = spb ^ ((srow & 7) << 4);

  auto stage = [&](int kt, int buf) {
    int kv0 = kt * 64;
    async_copy16((const char*)(Kp + (size_t)(kv0 + srow) * 64) + slb,
                 (char*)kT[buf] + soff);
    async_copy16((const char*)(Vp + (size_t)srow * 2048 + kv0) + slb,
                 (char*)vT[buf] + soff);
  };

  for (int seg = 0; seg < 2; ++seg) {
    const int qt = seg ? (7 - pi) : pi;
    const int q0 = qt << 8;
    const int qw = q0 + wid * 32;

    // Q B-fragments hoisted (n = q = c0, k = d contiguous)
    bf8 qfr[2][2];
    for (int qf = 0; qf < 2; qf++)
      for (int ks = 0; ks < 2; ks++)
        qfr[qf][ks] = *(const bf8*)((const char*)Qp +
                                    (size_t)(qw + qf * 16 + c0) * 128 + ks * 64 + g * 16);

    f4 accO[2][4];
    for (int i = 0; i < 2; i++)
      for (int j = 0; j < 4; j++) accO[i][j] = (f4)0.0f;
    float mrun[2] = {-INFINITY, -INFINITY}, lrun[2] = {0.f, 0.f};

    const int nkt = (q0 >> 6) + 4;               // 4*qt + 4 steps
    stage(0, 0);
    stage(1, 1);
    asm volatile("s_waitcnt vmcnt(2)" ::: "memory");
    __builtin_amdgcn_s_barrier();
    __builtin_amdgcn_sched_barrier(0);

    for (int kt = 0; kt < nkt; ++kt) {
      if (kt + 2 < nkt) stage(kt + 2, (kt + 2) % 3);
      const char* kbuf = (const char*)kT[kt % 3];
      const char* vbuf = (const char*)vT[kt % 3];
      const int kv0 = kt * 64;

      // S^T = K Q^T  (m = kv, n = q); kf loaded per-ks to halve live range
      f4 s[2][4];
      for (int i = 0; i < 2; i++)
        for (int j = 0; j < 4; j++) s[i][j] = (f4)0.0f;
#pragma unroll
      for (int ks = 0; ks < 2; ks++) {
        int cb = ks * 64 + g * 16;
        bf8 kf[4];
#pragma unroll
        for (int kvf = 0; kvf < 4; kvf++) {
          int row = kvf * 16 + c0;
          kf[kvf] = *(const bf8*)(kbuf + (row << 7) + (cb ^ ((row & 7) << 4)));
        }
        __builtin_amdgcn_s_setprio(1);
#pragma unroll
        for (int kvf = 0; kvf < 4; kvf++)
#pragma unroll
          for (int qf = 0; qf < 2; qf++)
            s[qf][kvf] = mfma16(kf[kvf], qfr[qf][ks], s[qf][kvf]);
        __builtin_amdgcn_s_setprio(0);
      }

      // scale to log2 domain; mask only if tile can contain kv > q_min (= qw)
      if (kv0 + 63 > qw) {
#pragma unroll
        for (int qf = 0; qf < 2; qf++) {
          int q = qw + qf * 16 + c0;
#pragma unroll
          for (int kvf = 0; kvf < 4; kvf++)
#pragma unroll
            for (int r = 0; r < 4; r++) {
              int kv = kv0 + kvf * 16 + 4 * g + r;
              float v = s[qf][kvf][r] * sc;
              s[qf][kvf][r] = (kv > q) ? -INFINITY : v;
            }
        }
      } else {
#pragma unroll
        for (int qf = 0; qf < 2; qf++)
#pragma unroll
          for (int kvf = 0; kvf < 4; kvf++)
#pragma unroll
            for (int r = 0; r < 4; r++) s[qf][kvf][r] *= sc;
      }

      // online softmax: lane-local reduce + 2 shfl_xor; defer-max THR=8 (log2 units)
      bf4 pfrag[2][4];
#pragma unroll
      for (int qf = 0; qf < 2; qf++) {
        float mx = s[qf][0][0];
#pragma unroll
        for (int kvf = 0; kvf < 4; kvf++)
#pragma unroll
          for (int r = 0; r < 4; r++) mx = fmaxf(mx, s[qf][kvf][r]);
        mx = fmaxf(mx, __shfl_xor(mx, 16));
        mx = fmaxf(mx, __shfl_xor(mx, 32));
        if (__any(mx > mrun[qf] + 8.0f)) {
          float mn = fmaxf(mrun[qf], mx);
          float pc = fexp2(mrun[qf] - mn);
          lrun[qf] *= pc;
#pragma unroll
          for (int df = 0; df < 4; df++)
#pragma unroll
            for (int r = 0; r < 4; r++) accO[qf][df][r] *= pc;
          mrun[qf] = mn;
        }
        float m = mrun[qf];
        float ls = 0.f;
#pragma unroll
        for (int kvf = 0; kvf < 4; kvf++) {
          float p0 = fexp2(s[qf][kvf][0] - m);
          float p1 = fexp2(s[qf][kvf][1] - m);
          float p2 = fexp2(s[qf][kvf][2] - m);
          float p3 = fexp2(s[qf][kvf][3] - m);
          ls += (p0 + p1) + (p2 + p3);
          union { unsigned u[2]; bf4 v; } uu;
          uu.u[0] = cvtpk_bf16(p0, p1);
          uu.u[1] = cvtpk_bf16(p2, p3);
          pfrag[qf][kvf] = uu.v;
        }
        ls += __shfl_xor(ls, 16);
        ls += __shfl_xor(ls, 32);
        lrun[qf] += ls;
      }

      // O^T += V^T P^T  via 16x16x16 (A = V^T rows d, B = P fragment direct from regs)
#pragma unroll
      for (int kvf = 0; kvf < 4; kvf++) {
        bf4 vf[4];
        int cb = kvf * 32 + g * 8;
#pragma unroll
        for (int df = 0; df < 4; df++) {
          int row = df * 16 + c0;
          vf[df] = *(const bf4*)(vbuf + (row << 7) + (cb ^ ((row & 7) << 4)));
        }
        __builtin_amdgcn_s_setprio(1);
#pragma unroll
        for (int df = 0; df < 4; df++)
#pragma unroll
          for (int qf = 0; qf < 2; qf++)
            accO[qf][df] = mfma16x16(vf[df], pfrag[qf][kvf], accO[qf][df]);
        __builtin_amdgcn_s_setprio(0);
      }

      // end-of-step: counted wait (stage kt+1 resident per-wave), then barrier
      if (kt + 2 < nkt)      asm volatile("s_waitcnt vmcnt(2)" ::: "memory");
      else if (kt + 1 < nkt) asm volatile("s_waitcnt vmcnt(0)" ::: "memory");
      __builtin_amdgcn_s_barrier();
      __builtin_amdgcn_sched_barrier(0);
    }

    // write out: O^T regs -> attnOut [B*L][1024]; d = df*16+4g+r contiguous -> 8B stores
    for (int qf = 0; qf < 2; qf++) {
      float inv = 1.0f / lrun[qf];
      int q = qw + qf * 16 + c0;
      for (int df = 0; df < 4; df++) {
        ushort4 o;
        o.x = f2bf(accO[qf][df][0] * inv);
        o.y = f2bf(accO[qf][df][1] * inv);
        o.z = f2bf(accO[qf][df][2] * inv);
        o.w = f2bf(accO[qf][df][3] * inv);
        int d = df * 16 + 4 * g;
        *(ushort4*)&attnOut[(size_t)(bb * 2048 + q) * 1024 + h * 64 + d] = o;
      }
    }
  }
}

// ---------------- launch ----------------

extern "C" void kernel_launch(void* const* d_in, const int* in_sizes, int n_in,
                              void* d_out, int out_size, void* d_ws, size_t ws_size,
                              hipStream_t stream) {
  const float* x      = (const float*)d_in[0];
  const float* qkv_w  = (const float*)d_in[1];
  const float* qkv_b  = (const float*)d_in[2];
  const float* proj_w = (const float*)d_in[3];
  const float* proj_b = (const float*)d_in[4];
  float* out = (float*)d_out;

  char* ws = (char*)d_ws;
  u16* xb      = (u16*)ws;  ws += (size_t)8192 * 1024 * 2;
  u16* wqkvT   = (u16*)ws;  ws += (size_t)3072 * 1024 * 2;
  u16* wprojT  = (u16*)ws;  ws += (size_t)1024 * 1024 * 2;
  float* cosT  = (float*)ws; ws += (size_t)2048 * 32 * 4;
  float* sinT  = (float*)ws; ws += (size_t)2048 * 32 * 4;
  u16* Qb      = (u16*)ws;  ws += (size_t)64 * 2048 * 64 * 2;
  u16* Kb      = (u16*)ws;  ws += (size_t)64 * 2048 * 64 * 2;
  u16* Vt      = (u16*)ws;  ws += (size_t)64 * 2048 * 64 * 2;
  u16* attnOut = (u16*)ws;  ws += (size_t)8192 * 1024 * 2;
  // total ws usage ~92.3 MB

  convert_bf16_k<<<8192, 256, 0, stream>>>(x, xb, 8192 * 1024 / 4);
  {
    dim3 tg(16, 48);
    transpose_bf16_k<<<tg, 256, 0, stream>>>(qkv_w, wqkvT, 1024, 3072);
  }
  {
    dim3 tg(16, 16);
    transpose_bf16_k<<<tg, 256, 0, stream>>>(proj_w, wprojT, 1024, 1024);
  }
  rope_tables_k<<<256, 256, 0, stream>>>(cosT, sinT);

  gemm_bt<1><<<64 * 24, 256, 0, stream>>>(xb, wqkvT, qkv_b, nullptr,
                                          Qb, Kb, Vt, cosT, sinT, 8192, 3072, 1024);
  attn_fwd<<<256, 512, 0, stream>>>(Qb, Kb, Vt, attnOut);
  gemm_bt<0><<<64 * 8, 256, 0, stream>>>(attnOut, wprojT, proj_b, out,
                                         nullptr, nullptr, nullptr, nullptr, nullptr,
                                         8192, 1024, 1024);
}

// Round 7
// 222.391 us; speedup vs baseline: 1.3602x; 1.3602x over previous
//
#include <hip/hip_runtime.h>
#include <hip/hip_bf16.h>
#include <math.h>

// Problem constants: B=4, L=2048, D=1024, H=16, hd=64
// M = B*L = 8192, QKV N = 3072, proj N = 1024, K = 1024

typedef unsigned short u16;
typedef __attribute__((ext_vector_type(8))) short bf8;   // 8 bf16 = 4 VGPR (MFMA A/B frag, K=32)
typedef __attribute__((ext_vector_type(4))) short bf4;   // 4 bf16 = 2 VGPR (MFMA A/B frag, K=16)
typedef __attribute__((ext_vector_type(4))) float f4;    // MFMA C/D frag

__device__ __forceinline__ u16 f2bf(float f) {
  unsigned int u = __float_as_uint(f);
  unsigned int r = (u + 0x7fffu + ((u >> 16) & 1u)) >> 16;
  return (u16)r;
}

__device__ __forceinline__ unsigned cvtpk_bf16(float lo, float hi) {
  unsigned r;
  asm("v_cvt_pk_bf16_f32 %0, %1, %2" : "=v"(r) : "v"(lo), "v"(hi));
  return r;
}

__device__ __forceinline__ f4 mfma16(bf8 a, bf8 b, f4 c) {
  return __builtin_amdgcn_mfma_f32_16x16x32_bf16(a, b, c, 0, 0, 0);
}

__device__ __forceinline__ f4 mfma16x16(bf4 a, bf4 b, f4 c) {
#if __has_builtin(__builtin_amdgcn_mfma_f32_16x16x16bf16_1k)
  return __builtin_amdgcn_mfma_f32_16x16x16bf16_1k(a, b, c, 0, 0, 0);
#elif __has_builtin(__builtin_amdgcn_mfma_f32_16x16x16_bf16)
  return __builtin_amdgcn_mfma_f32_16x16x16_bf16(a, b, c, 0, 0, 0);
#else
  f4 d;
  asm volatile("v_mfma_f32_16x16x16_bf16 %0, %1, %2, %3"
               : "=v"(d) : "v"(a), "v"(b), "v"(c));
  return d;
#endif
}

__device__ __forceinline__ float fexp2(float x) {
#if __has_builtin(__builtin_amdgcn_exp2f)
  return __builtin_amdgcn_exp2f(x);
#else
  return exp2f(x);
#endif
}

__device__ __forceinline__ void async_copy16(const void* gsrc, void* ldst) {
  __builtin_amdgcn_global_load_lds(
      (__attribute__((address_space(1))) void*)gsrc,
      (__attribute__((address_space(3))) void*)ldst,
      16, 0, 0);
}

// ---------------- prep kernels ----------------

__global__ __launch_bounds__(256) void convert_bf16_k(const float* __restrict__ in,
                                                      u16* __restrict__ out, int n4) {
  int i = blockIdx.x * blockDim.x + threadIdx.x;
  if (i < n4) {
    float4 v = ((const float4*)in)[i];
    ushort4 o;
    o.x = f2bf(v.x); o.y = f2bf(v.y); o.z = f2bf(v.z); o.w = f2bf(v.w);
    ((ushort4*)out)[i] = o;
  }
}

// in [K][N] f32 row-major -> out [N][K] bf16 row-major (B^T layout). 64x64 tiles.
__global__ __launch_bounds__(256) void transpose_bf16_k(const float* __restrict__ in,
                                                        u16* __restrict__ out, int K, int N) {
  __shared__ float t[64][65];
  int k0 = blockIdx.x * 64;
  int n0 = blockIdx.y * 64;
  int tx = threadIdx.x & 63, ty = threadIdx.x >> 6;  // 4 rows per pass
  for (int i = 0; i < 16; i++) {
    int r = ty + i * 4;
    t[r][tx] = in[(size_t)(k0 + r) * N + n0 + tx];
  }
  __syncthreads();
  for (int i = 0; i < 16; i++) {
    int r = ty + i * 4;
    out[(size_t)(n0 + r) * K + k0 + tx] = f2bf(t[tx][r]);
  }
}

// cos/sin tables [2048][32] f32
__global__ __launch_bounds__(256) void rope_tables_k(float* __restrict__ cosT,
                                                     float* __restrict__ sinT) {
  int i = blockIdx.x * blockDim.x + threadIdx.x;  // 65536
  int l = i >> 5, j = i & 31;
  float inv = powf(10000.0f, -(float)j / 32.0f);
  float f = (float)l * inv;
  cosT[i] = cosf(f);
  sinT[i] = sinf(f);
}

// ---------------- GEMM (A[M][K]bf16 x Bt[N][K]bf16) ---- R2-proven structure ----
// 128x128 tile, BK=64, 4 waves (2x2), each wave 64x64 (4x4 frags of 16x16x32).
// LDS tiles are [128 rows][128 bytes] with XOR swizzle byte ^= ((row&7)<<4),
// applied on the global SOURCE address (global_load_lds writes linearly) and on reads.
// EPI==0: out f32 += bias. EPI==1: fused bias+RoPE epilogue -> Qb/Kb [bh][l][64], Vt [bh][64][l].

template <int EPI>
__global__ __launch_bounds__(256, 2) void gemm_bt(
    const u16* __restrict__ A, const u16* __restrict__ Bt, const float* __restrict__ bias,
    float* __restrict__ outF,
    u16* __restrict__ Qb, u16* __restrict__ Kb, u16* __restrict__ Vt,
    const float* __restrict__ cosT, const float* __restrict__ sinT,
    int M, int N, int K) {
  __shared__ __attribute__((aligned(16))) u16 lA[128 * 64];
  __shared__ __attribute__((aligned(16))) u16 lB[128 * 64];
  const int tid = threadIdx.x;
  const int lane = tid & 63, wid = tid >> 6;
  const int nTilesN = N >> 7;
  const int bm = blockIdx.x / nTilesN, bn = blockIdx.x % nTilesN;
  const int m0 = bm << 7, n0 = bn << 7;
  const int wm = (wid >> 1) << 6, wn = (wid & 1) << 6;
  const int g = lane >> 4, c0 = lane & 15;

  f4 acc[4][4];
  for (int i = 0; i < 4; i++)
    for (int j = 0; j < 4; j++) acc[i][j] = (f4)0.0f;

  for (int k0 = 0; k0 < K; k0 += 64) {
    __syncthreads();
    for (int i = 0; i < 4; i++) {
      int chunk = i * 4 + wid;
      int p = chunk * 1024 + lane * 16;
      int row = p >> 7, pb = p & 127;
      int lb = pb ^ ((row & 7) << 4);
      async_copy16((const char*)(A + (size_t)(m0 + row) * K + k0) + lb,
                   (char*)lA + chunk * 1024);
    }
    for (int i = 0; i < 4; i++) {
      int chunk = i * 4 + wid;
      int p = chunk * 1024 + lane * 16;
      int row = p >> 7, pb = p & 127;
      int lb = pb ^ ((row & 7) << 4);
      async_copy16((const char*)(Bt + (size_t)(n0 + row) * K + k0) + lb,
                   (char*)lB + chunk * 1024);
    }
    __syncthreads();
    bf8 a[4][2], b[4][2];
    for (int ks = 0; ks < 2; ks++) {
      int cb = ks * 64 + g * 16;
      for (int mf = 0; mf < 4; mf++) {
        int row = wm + mf * 16 + c0;
        a[mf][ks] = *(const bf8*)((const char*)lA + (row << 7) + (cb ^ ((row & 7) << 4)));
      }
      for (int nf = 0; nf < 4; nf++) {
        int row = wn + nf * 16 + c0;
        b[nf][ks] = *(const bf8*)((const char*)lB + (row << 7) + (cb ^ ((row & 7) << 4)));
      }
    }
    for (int ks = 0; ks < 2; ks++)
      for (int mf = 0; mf < 4; mf++)
        for (int nf = 0; nf < 4; nf++)
          acc[mf][nf] = mfma16(a[mf][ks], b[nf][ks], acc[mf][nf]);
  }

  // C frag mapping (verified m89/m91): col = c0 + 16*nf (+wn+n0), row = 4*g + reg (+16*mf+wm+m0)
  if (EPI == 0) {
    for (int nf = 0; nf < 4; nf++) {
      int col = n0 + wn + nf * 16 + c0;
      float bv = bias[col];
      for (int mf = 0; mf < 4; mf++) {
        int rowb = m0 + wm + mf * 16 + g * 4;
        for (int r = 0; r < 4; r++)
          outF[(size_t)(rowb + r) * N + col] = acc[mf][nf][r] + bv;
      }
    }
  } else {
    for (int nf = 0; nf < 4; nf++) {
      int col = n0 + wn + nf * 16 + c0;
      int sec = col >> 10;          // 0=q 1=k 2=v
      int hc = col & 1023;
      int h = hc >> 6, d = hc & 63;
      float bv = bias[col];
      int pcol = n0 + wn + (nf ^ 2) * 16 + c0;  // RoPE partner col (d +/- 32), same lane
      float pbv = bias[pcol];
      for (int mf = 0; mf < 4; mf++) {
        int rowb = m0 + wm + mf * 16 + g * 4;
        for (int r = 0; r < 4; r++) {
          int row = rowb + r;
          int bb = row >> 11, l = row & 2047;
          int bh = bb * 16 + h;
          float v = acc[mf][nf][r] + bv;
          if (sec == 2) {
            Vt[((size_t)bh * 64 + d) * 2048 + l] = f2bf(v);  // V stored transposed [bh][d][l]
          } else {
            int dm = d & 31;
            float cz = cosT[l * 32 + dm], sz = sinT[l * 32 + dm];
            float pv = acc[mf][nf ^ 2][r] + pbv;
            float o = (d < 32) ? (v * cz - pv * sz) : (v * cz + pv * sz);
            u16* dst = (sec == 0) ? Qb : Kb;
            dst[((size_t)bh * 2048 + l) * 64 + d] = f2bf(o);
          }
        }
      }
    }
  }
}

// ---------------- flash attention v4 (R2 TLP geometry + counted-vmcnt staging) ----------------
// 512 blocks = 64 bh x 8 q-tile-pairs (q-tile = 128 rows); block handles q-tiles (pi)
// and (15-pi): exactly 34 KV-steps each -> balanced. 256 threads = 4 waves x 32 q-rows.
// LDS 48KB (3 buffers) -> 2 blocks/CU co-resident: barrier stalls of one block are
// hidden by the other (R6 regression root cause: 512-thr blocks = 1/CU = no TLP).
// 3-buffer lag-2 staging, counted vmcnt(4) per step (stage = 4 copies), raw s_barrier,
// never vmcnt(0) mid-loop. Mask rule: needed iff kv0+63 > qw (wave q_min).
// S^T = mfma(K,Q); softmax lane-local + 2 shfl_xor; P directly the PV B-fragment.
// cvt_pk bf16 pack (T12), defer-max THR=8 (T13), setprio (T5).
__global__ __launch_bounds__(256, 2) void attn_fwd(
    const u16* __restrict__ Qb, const u16* __restrict__ Kb, const u16* __restrict__ Vt,
    u16* __restrict__ attnOut) {
  __shared__ __attribute__((aligned(16))) u16 kT[3][64 * 64];
  __shared__ __attribute__((aligned(16))) u16 vT[3][64 * 64];
  const int tid = threadIdx.x, lane = tid & 63, wid = tid >> 6;
  // XCD swizzle: 64 consecutive lblk (8 bh) per XCD -> K/V 4MB = one L2
  const int pblk = blockIdx.x;                 // nwg = 512
  const int lblk = ((pblk & 7) << 6) | (pblk >> 3);
  const int bh = lblk >> 3, pi = lblk & 7;
  const int bb = bh >> 4, h = bh & 15;
  const u16* Qp = Qb + (size_t)bh * 2048 * 64;
  const u16* Kp = Kb + (size_t)bh * 2048 * 64;
  const u16* Vp = Vt + (size_t)bh * 64 * 2048;   // [64 d][2048 l]
  const int g = lane >> 4, c0 = lane & 15;
  const float sc = 0.125f * 1.4426950408889634f;  // scale * log2(e)

  auto stage = [&](int kt, int buf) {            // 4 copies: 2 K-chunks + 2 V-chunks
    int kv0 = kt * 64;
#pragma unroll
    for (int c = 0; c < 2; c++) {
      int off = c * 4096 + tid * 16;
      int row = off >> 7, pb = off & 127;
      int lb = pb ^ ((row & 7) << 4);
      async_copy16((const char*)(Kp + (size_t)(kv0 + row) * 64) + lb,
                   (char*)kT[buf] + off);
      async_copy16((const char*)(Vp + (size_t)row * 2048 + kv0) + lb,
                   (char*)vT[buf] + off);
    }
  };

  for (int seg = 0; seg < 2; ++seg) {
    const int qt = seg ? (15 - pi) : pi;
    const int q0 = qt << 7;
    const int qw = q0 + wid * 32;

    // Q B-fragments hoisted (n = q = c0, k = d contiguous)
    bf8 qfr[2][2];
    for (int qf = 0; qf < 2; qf++)
      for (int ks = 0; ks < 2; ks++)
        qfr[qf][ks] = *(const bf8*)((const char*)Qp +
                                    (size_t)(qw + qf * 16 + c0) * 128 + ks * 64 + g * 16);

    f4 accO[2][4];
    for (int i = 0; i < 2; i++)
      for (int j = 0; j < 4; j++) accO[i][j] = (f4)0.0f;
    float mrun[2] = {-INFINITY, -INFINITY}, lrun[2] = {0.f, 0.f};

    const int nkt = (q0 >> 6) + 2;               // 2*qt + 2 steps
    stage(0, 0);
    stage(1, 1);
    asm volatile("s_waitcnt vmcnt(4)" ::: "memory");
    __builtin_amdgcn_s_barrier();

    for (int kt = 0; kt < nkt; ++kt) {
      if (kt + 2 < nkt) stage(kt + 2, (kt + 2) % 3);
      const char* kbuf = (const char*)kT[kt % 3];
      const char* vbuf = (const char*)vT[kt % 3];
      const int kv0 = kt * 64;

      // S^T = K Q^T  (m = kv, n = q); kf loaded per-ks to halve live range
      f4 s[2][4];
      for (int i = 0; i < 2; i++)
        for (int j = 0; j < 4; j++) s[i][j] = (f4)0.0f;
#pragma unroll
      for (int ks = 0; ks < 2; ks++) {
        int cb = ks * 64 + g * 16;
        bf8 kf[4];
#pragma unroll
        for (int kvf = 0; kvf < 4; kvf++) {
          int row = kvf * 16 + c0;
          kf[kvf] = *(const bf8*)(kbuf + (row << 7) + (cb ^ ((row & 7) << 4)));
        }
        __builtin_amdgcn_s_setprio(1);
#pragma unroll
        for (int kvf = 0; kvf < 4; kvf++)
#pragma unroll
          for (int qf = 0; qf < 2; qf++)
            s[qf][kvf] = mfma16(kf[kvf], qfr[qf][ks], s[qf][kvf]);
        __builtin_amdgcn_s_setprio(0);
      }

      // scale to log2 domain; mask only if tile can contain kv > q_min (= qw)
      if (kv0 + 63 > qw) {
#pragma unroll
        for (int qf = 0; qf < 2; qf++) {
          int q = qw + qf * 16 + c0;
#pragma unroll
          for (int kvf = 0; kvf < 4; kvf++)
#pragma unroll
            for (int r = 0; r < 4; r++) {
              int kv = kv0 + kvf * 16 + 4 * g + r;
              float v = s[qf][kvf][r] * sc;
              s[qf][kvf][r] = (kv > q) ? -INFINITY : v;
            }
        }
      } else {
#pragma unroll
        for (int qf = 0; qf < 2; qf++)
#pragma unroll
          for (int kvf = 0; kvf < 4; kvf++)
#pragma unroll
            for (int r = 0; r < 4; r++) s[qf][kvf][r] *= sc;
      }

      // online softmax: lane-local reduce + 2 shfl_xor; defer-max THR=8 (log2 units)
      bf4 pfrag[2][4];
#pragma unroll
      for (int qf = 0; qf < 2; qf++) {
        float mx = s[qf][0][0];
#pragma unroll
        for (int kvf = 0; kvf < 4; kvf++)
#pragma unroll
          for (int r = 0; r < 4; r++) mx = fmaxf(mx, s[qf][kvf][r]);
        mx = fmaxf(mx, __shfl_xor(mx, 16));
        mx = fmaxf(mx, __shfl_xor(mx, 32));
        if (__any(mx > mrun[qf] + 8.0f)) {
          float mn = fmaxf(mrun[qf], mx);
          float pc = fexp2(mrun[qf] - mn);
          lrun[qf] *= pc;
#pragma unroll
          for (int df = 0; df < 4; df++)
#pragma unroll
            for (int r = 0; r < 4; r++) accO[qf][df][r] *= pc;
          mrun[qf] = mn;
        }
        float m = mrun[qf];
        float ls = 0.f;
#pragma unroll
        for (int kvf = 0; kvf < 4; kvf++) {
          float p0 = fexp2(s[qf][kvf][0] - m);
          float p1 = fexp2(s[qf][kvf][1] - m);
          float p2 = fexp2(s[qf][kvf][2] - m);
          float p3 = fexp2(s[qf][kvf][3] - m);
          ls += (p0 + p1) + (p2 + p3);
          union { unsigned u[2]; bf4 v; } uu;
          uu.u[0] = cvtpk_bf16(p0, p1);
          uu.u[1] = cvtpk_bf16(p2, p3);
          pfrag[qf][kvf] = uu.v;
        }
        ls += __shfl_xor(ls, 16);
        ls += __shfl_xor(ls, 32);
        lrun[qf] += ls;
      }

      // O^T += V^T P^T  via 16x16x16 (A = V^T rows d, B = P fragment direct from regs)
#pragma unroll
      for (int kvf = 0; kvf < 4; kvf++) {
        bf4 vf[4];
        int cb = kvf * 32 + g * 8;
#pragma unroll
        for (int df = 0; df < 4; df++) {
          int row = df * 16 + c0;
          vf[df] = *(const bf4*)(vbuf + (row << 7) + (cb ^ ((row & 7) << 4)));
        }
        __builtin_amdgcn_s_setprio(1);
#pragma unroll
        for (int df = 0; df < 4; df++)
#pragma unroll
          for (int qf = 0; qf < 2; qf++)
            accO[qf][df] = mfma16x16(vf[df], pfrag[qf][kvf], accO[qf][df]);
        __builtin_amdgcn_s_setprio(0);
      }

      // end-of-step: counted wait (stage kt+1 resident), then barrier
      if (kt + 2 < nkt)      asm volatile("s_waitcnt vmcnt(4)" ::: "memory");
      else if (kt + 1 < nkt) asm volatile("s_waitcnt vmcnt(0)" ::: "memory");
      __builtin_amdgcn_s_barrier();
    }

    // write out: O^T regs -> attnOut [B*L][1024]; d = df*16+4g+r contiguous -> 8B stores
    for (int qf = 0; qf < 2; qf++) {
      float inv = 1.0f / lrun[qf];
      int q = qw + qf * 16 + c0;
      for (int df = 0; df < 4; df++) {
        ushort4 o;
        o.x = f2bf(accO[qf][df][0] * inv);
        o.y = f2bf(accO[qf][df][1] * inv);
        o.z = f2bf(accO[qf][df][2] * inv);
        o.w = f2bf(accO[qf][df][3] * inv);
        int d = df * 16 + 4 * g;
        *(ushort4*)&attnOut[(size_t)(bb * 2048 + q) * 1024 + h * 64 + d] = o;
      }
    }
  }
}

// ---------------- launch ----------------

extern "C" void kernel_launch(void* const* d_in, const int* in_sizes, int n_in,
                              void* d_out, int out_size, void* d_ws, size_t ws_size,
                              hipStream_t stream) {
  const float* x      = (const float*)d_in[0];
  const float* qkv_w  = (const float*)d_in[1];
  const float* qkv_b  = (const float*)d_in[2];
  const float* proj_w = (const float*)d_in[3];
  const float* proj_b = (const float*)d_in[4];
  float* out = (float*)d_out;

  char* ws = (char*)d_ws;
  u16* xb      = (u16*)ws;  ws += (size_t)8192 * 1024 * 2;
  u16* wqkvT   = (u16*)ws;  ws += (size_t)3072 * 1024 * 2;
  u16* wprojT  = (u16*)ws;  ws += (size_t)1024 * 1024 * 2;
  float* cosT  = (float*)ws; ws += (size_t)2048 * 32 * 4;
  float* sinT  = (float*)ws; ws += (size_t)2048 * 32 * 4;
  u16* Qb      = (u16*)ws;  ws += (size_t)64 * 2048 * 64 * 2;
  u16* Kb      = (u16*)ws;  ws += (size_t)64 * 2048 * 64 * 2;
  u16* Vt      = (u16*)ws;  ws += (size_t)64 * 2048 * 64 * 2;
  u16* attnOut = (u16*)ws;  ws += (size_t)8192 * 1024 * 2;
  // total ws usage ~92.3 MB

  convert_bf16_k<<<8192, 256, 0, stream>>>(x, xb, 8192 * 1024 / 4);
  {
    dim3 tg(16, 48);
    transpose_bf16_k<<<tg, 256, 0, stream>>>(qkv_w, wqkvT, 1024, 3072);
  }
  {
    dim3 tg(16, 16);
    transpose_bf16_k<<<tg, 256, 0, stream>>>(proj_w, wprojT, 1024, 1024);
  }
  rope_tables_k<<<256, 256, 0, stream>>>(cosT, sinT);

  gemm_bt<1><<<64 * 24, 256, 0, stream>>>(xb, wqkvT, qkv_b, nullptr,
                                          Qb, Kb, Vt, cosT, sinT, 8192, 3072, 1024);
  attn_fwd<<<512, 256, 0, stream>>>(Qb, Kb, Vt, attnOut);
  gemm_bt<0><<<64 * 8, 256, 0, stream>>>(attnOut, wprojT, proj_b, out,
                                         nullptr, nullptr, nullptr, nullptr, nullptr,
                                         8192, 1024, 1024);
}